// Round 7
// baseline (190.718 us; speedup 1.0000x reference)
//
#include <hip/hip_runtime.h>
#include <hip/hip_bf16.h>
#include <cstdint>
#include <cstddef>

#define B_DIM 256
#define T_DIM 256
#define EMB   384
#define HEAD  64

typedef __attribute__((ext_vector_type(8))) short bf16x8;
typedef __attribute__((ext_vector_type(4))) float f32x4;
typedef __attribute__((ext_vector_type(4))) unsigned int u32x4;

__device__ __forceinline__ unsigned short f2bf(float f) {
    union { float f; unsigned int u; } v; v.f = f;
    unsigned int r = v.u + 0x7fffu + ((v.u >> 16) & 1u);  // RNE
    return (unsigned short)(r >> 16);
}

__device__ __forceinline__ unsigned int pkbf(float a, float b) {
#if __has_builtin(__builtin_amdgcn_cvt_pk_bf16_f32)
    typedef __attribute__((ext_vector_type(2))) __bf16 bf16x2_t;
    bf16x2_t r = __builtin_amdgcn_cvt_pk_bf16_f32(a, b);
    return *(unsigned int*)&r;
#else
    return (unsigned)f2bf(a) | ((unsigned)f2bf(b) << 16);
#endif
}

// ---------------------------------------------------------------------------
// Kernel 0: W prep — Wq|Wk|Wv fp32 [384][64] -> Wb bf16, chunk-permuted.
// Chunk g = kkstep*1536 + r*8 + cs holds the 8 k-values of source chunk
// c = cs ^ (r&7) of output-col r in k-step kkstep. Unchanged from v1.
// ---------------------------------------------------------------------------
__global__ void wprep_kernel(const float* __restrict__ Wq, const float* __restrict__ Wk,
                             const float* __restrict__ Wv, unsigned short* __restrict__ Wb) {
    int g = blockIdx.x * blockDim.x + threadIdx.x;
    if (g >= 9216) return;                 // 6 k-steps * 1536 chunks
    int kkstep = g / 1536, rem = g - kkstep * 1536;
    int r = rem >> 3, cs = rem & 7, c = cs ^ (r & 7);
    const float* W = (r < 64) ? Wq : (r < 128) ? Wk : Wv;
    int h = r & 63;
    unsigned short tmp[8];
#pragma unroll
    for (int e = 0; e < 8; ++e) {
        int k = kkstep * 64 + c * 8 + e;
        tmp[e] = f2bf(W[k * HEAD + h]);
    }
    *(u32x4*)(Wb + (size_t)g * 8) = *(u32x4*)tmp;
}

// ---------------------------------------------------------------------------
// Fused kernel v8: one block per batch, 1024 threads (16 waves), 1 block/CU.
//
// Diagnosis driving v8: four structurally different variants (v1 LDS dbuf,
// v4 LDS stash, v6 16-wave, v7 producer/consumer) ALL land at fused 50-58 us
// with every pipe <15% busy. The invariant: a barrier-stepped GEMM k-loop.
// __syncthreads each step drains vmcnt/lgkmcnt and re-couples all waves to
// the same dependent chain (glds -> barrier -> ds_read -> MFMA -> cvt ->
// ds_write -> barrier); the slowest chain gates everyone, 12x per kernel,
// and no chain overlaps across steps. More waves / role-splits can't fix a
// lockstep. v8 deletes the lockstep:
//   ZERO-LDS GEMM: each wave (4x4 grid, 64 rows x 48 cols, acc[4][3])
//   loads A directly global->reg from fp32 x (per frag: lane reads 32 B
//   contiguous; qd-groups tile a full 128 B line per row -> 100% line use,
//   each line read once device-wide) and converts via pkbf in-register.
//   B frags come directly from Wb (same swizzle-index formula as the old
//   LDS path, base swapped to global; Wb is 147 KB -> L2-resident).
//   NO barriers, NO LDS, NO waitcnt drains in the k-loop: 16 independent
//   waves/CU, pure reg flow. #pragma unroll 1 on kk bounds VGPR pressure.
// One __syncthreads before attention. Scatter + attention = v7 verbatim.
// LDS: p2 only = 144,384 B.
// ---------------------------------------------------------------------------
__global__ __launch_bounds__(1024, 1) void fused_kernel(const float* __restrict__ x,
                                                        const unsigned short* __restrict__ Wb,
                                                        float* __restrict__ out) {
    __shared__ struct {
        unsigned short qs[256][72]; unsigned short ks[256][72];
        unsigned short vT[64][264]; unsigned short Ps[16][16][72];
    } sm;                                                            // 144,384 B

    const int tid = threadIdx.x;
    const int w = tid >> 6, lane = tid & 63, qd = lane >> 4, l15 = lane & 15;
    const int wm = w >> 2, wn = w & 3;            // 4x4 wave grid: 64 rows x 48 cols
    const int b = blockIdx.x;
    const float* xb = x + (size_t)b * T_DIM * EMB;

    f32x4 acc[4][3];
#pragma unroll
    for (int mt = 0; mt < 4; ++mt)
#pragma unroll
        for (int nt = 0; nt < 3; ++nt) acc[mt][nt] = (f32x4){0.f, 0.f, 0.f, 0.f};

    // ---- GEMM: direct global->reg, barrier-free ----
#pragma unroll 1
    for (int kk = 0; kk < 6; ++kk) {
#pragma unroll
        for (int kb = 0; kb < 2; ++kb) {
            float4 xa[4][2];
#pragma unroll
            for (int mt = 0; mt < 4; ++mt) {
                const float* p = xb + (size_t)(64 * wm + 16 * mt + l15) * EMB
                                 + kk * 64 + kb * 32 + 8 * qd;
                xa[mt][0] = *(const float4*)p;
                xa[mt][1] = *(const float4*)(p + 4);
            }
            bf16x8 bb[3];
#pragma unroll
            for (int nt = 0; nt < 3; ++nt) {
                int n = 48 * wn + 16 * nt + l15;
                bb[nt] = *(const bf16x8*)(Wb + (size_t)(kk * 1536 + n * 8 +
                                                        (((kb << 2) + qd) ^ (n & 7))) * 8);
            }
            bf16x8 a[4];
#pragma unroll
            for (int mt = 0; mt < 4; ++mt) {
                union { unsigned int u[4]; bf16x8 v; } cv;
                cv.u[0] = pkbf(xa[mt][0].x, xa[mt][0].y);
                cv.u[1] = pkbf(xa[mt][0].z, xa[mt][0].w);
                cv.u[2] = pkbf(xa[mt][1].x, xa[mt][1].y);
                cv.u[3] = pkbf(xa[mt][1].z, xa[mt][1].w);
                a[mt] = cv.v;
            }
#pragma unroll
            for (int mt = 0; mt < 4; ++mt)
#pragma unroll
                for (int nt = 0; nt < 3; ++nt)
                    acc[mt][nt] = __builtin_amdgcn_mfma_f32_16x16x32_bf16(a[mt], bb[nt], acc[mt][nt], 0, 0, 0);
        }
    }

    // scatter acc -> qs / ks / vT  (C/D layout: col=l15(ch), row=4*qd+reg(tok))
#pragma unroll
    for (int nt = 0; nt < 3; ++nt) {
        int n = 48 * wn + 16 * nt + l15;
        int arr = n >> 6, hh = n & 63;         // wave-uniform per (wn,nt)
        if (arr == 2) {                        // vT: token-contiguous -> packed b64
#pragma unroll
            for (int mt = 0; mt < 4; ++mt) {
                int tok0 = 64 * wm + 16 * mt + 4 * qd;
                *(uint2*)&sm.vT[hh][tok0] = make_uint2(
                    pkbf(acc[mt][nt][0], acc[mt][nt][1]),
                    pkbf(acc[mt][nt][2], acc[mt][nt][3]));
            }
        } else {
#pragma unroll
            for (int mt = 0; mt < 4; ++mt)
#pragma unroll
                for (int reg = 0; reg < 4; ++reg) {
                    int tok = 64 * wm + 16 * mt + 4 * qd + reg;
                    unsigned short val = f2bf(acc[mt][nt][reg]);
                    if (arr == 0) sm.qs[tok][hh] = val;
                    else          sm.ks[tok][hh] = val;
                }
        }
    }
    __syncthreads();       // q/k/vT ready (the kernel's only barrier)

    // ---------------- attention, fully in LDS (v6/v7, verified) ----------------
    // SIMD-balanced tile map: wave w (SIMD s=w&3, slot=w>>2) ->
    // slot 0: 2s, slot 1: 2s+1, slot 2: 15-2s, slot 3: 14-2s.
    const int slot = w >> 2, sid = w & 3;
    const int t = (slot < 2) ? (2 * sid + slot) : (15 - 2 * sid - (slot & 1));

    bf16x8 aq[2];
#pragma unroll
    for (int kbi = 0; kbi < 2; ++kbi)
        aq[kbi] = *(const bf16x8*)&sm.qs[16 * t + l15][32 * kbi + 8 * qd];

    f32x4 O[4];
    float l[4];
#pragma unroll
    for (int dn = 0; dn < 4; ++dn) O[dn] = (f32x4){0.f, 0.f, 0.f, 0.f};
#pragma unroll
    for (int reg = 0; reg < 4; ++reg) l[reg] = 0.f;

    const float cExp = 1.4426950408889634f / 19.595917942265423f; // log2(e)/sqrt(384)

    for (int jc = 0; jc <= (t >> 2); ++jc) {
        const int ntmax = min(3, t - 4 * jc);
        f32x4 S[4];
#pragma unroll
        for (int nt = 0; nt < 4; ++nt) {
            if (nt <= ntmax) {
                bf16x8 b0 = *(const bf16x8*)&sm.ks[64 * jc + 16 * nt + l15][8 * qd];
                bf16x8 b1 = *(const bf16x8*)&sm.ks[64 * jc + 16 * nt + l15][32 + 8 * qd];
                f32x4 s = __builtin_amdgcn_mfma_f32_16x16x32_bf16(aq[0], b0, (f32x4){0.f,0.f,0.f,0.f}, 0, 0, 0);
                s = __builtin_amdgcn_mfma_f32_16x16x32_bf16(aq[1], b1, s, 0, 0, 0);
                S[nt] = s;
            }
        }
#pragma unroll
        for (int nt = 0; nt < 4; ++nt) {
#pragma unroll
            for (int reg = 0; reg < 4; ++reg) {
                float p = 0.0f;
                if (nt <= ntmax) {
                    p = exp2f(S[nt][reg] * cExp);
                    if (4 * jc + nt == t && (l15 > 4 * qd + reg)) p = 0.0f;  // diagonal mask
                }
                l[reg] += p;
                sm.Ps[w][4 * qd + reg][16 * nt + l15] = f2bf(p);
            }
        }
        // C-layout -> A-layout via wave-private strip (no barrier needed)
        bf16x8 ap0 = *(const bf16x8*)&sm.Ps[w][l15][8 * qd];
        bf16x8 ap1 = *(const bf16x8*)&sm.Ps[w][l15][32 + 8 * qd];
#pragma unroll
        for (int dn = 0; dn < 4; ++dn) {
            bf16x8 bv0 = *(const bf16x8*)&sm.vT[16 * dn + l15][64 * jc + 8 * qd];
            bf16x8 bv1 = *(const bf16x8*)&sm.vT[16 * dn + l15][64 * jc + 32 + 8 * qd];
            O[dn] = __builtin_amdgcn_mfma_f32_16x16x32_bf16(ap0, bv0, O[dn], 0, 0, 0);
            O[dn] = __builtin_amdgcn_mfma_f32_16x16x32_bf16(ap1, bv1, O[dn], 0, 0, 0);
        }
    }

#pragma unroll
    for (int reg = 0; reg < 4; ++reg) {
        float s = l[reg];
        s += __shfl_xor(s, 1);
        s += __shfl_xor(s, 2);
        s += __shfl_xor(s, 4);
        s += __shfl_xor(s, 8);
        float inv = 1.0f / s;
        int row = 16 * t + 4 * qd + reg;
        float* dst = out + ((size_t)b * T_DIM + row) * HEAD;
#pragma unroll
        for (int dn = 0; dn < 4; ++dn)
            dst[16 * dn + l15] = O[dn][reg] * inv;
    }
}

// ---------------------------------------------------------------------------
extern "C" void kernel_launch(void* const* d_in, const int* in_sizes, int n_in,
                              void* d_out, int out_size, void* d_ws, size_t ws_size,
                              hipStream_t stream) {
    const float* x  = (const float*)d_in[0];
    const float* Wq = (const float*)d_in[1];
    const float* Wk = (const float*)d_in[2];
    const float* Wv = (const float*)d_in[3];
    float* out = (float*)d_out;

    unsigned short* Wb = (unsigned short*)d_ws;   // 9216*8 bf16 = 147 KB

    wprep_kernel<<<36, 256, 0, stream>>>(Wq, Wk, Wv, Wb);
    fused_kernel<<<B_DIM, 1024, 0, stream>>>(x, Wb, out);
}